// Round 17
// baseline (832.599 us; speedup 1.0000x reference)
//
#include <hip/hip_runtime.h>

#define B_   128
#define T_   16

typedef __bf16 bf16;
typedef __bf16 bf16x4 __attribute__((ext_vector_type(4)));
typedef __bf16 bf16x8 __attribute__((ext_vector_type(8)));
typedef float f32x4 __attribute__((ext_vector_type(4)));

#define GLL(SRC, DST) __builtin_amdgcn_global_load_lds( \
    (const __attribute__((address_space(1))) void*)(SRC), \
    (__attribute__((address_space(3))) void*)(DST), 16, 0, 0)

#define MFMA __builtin_amdgcn_mfma_f32_16x16x32_bf16
#define SLICE 524288   // 128*4096 elements per partial slice

__device__ __forceinline__ float sigf(float x) { return 1.f / (1.f + expf(-x)); }

// ---------------------------------------------------------------------------
// R2/R10-proven 64x64-tile GEMM core: BK=64, dbuf 32KB LDS, 4 waves x 32x32.
// ---------------------------------------------------------------------------
__device__ __forceinline__ void core64(
    bf16 (&As)[2][4096], bf16 (&Bs)[2][4096],
    const bf16* __restrict__ Ab, int lda,
    const bf16* __restrict__ Wb, int ldw,
    int nk, f32x4 (&acc)[4])
{
    const int tid = threadIdx.x, lane = tid & 63, wave = tid >> 6;
    const int srow = lane >> 3;
    const int scol = ((lane & 7) ^ srow) << 3;     // pre-swizzled source col
    const int wr = wave & 1, wc = wave >> 1;
    const int ln = lane & 15;
    const int rA0 = wr * 32 + ln;
    const int rB0 = wc * 32 + ln;
    const int swz = (lane & 7) << 4;
    const int kq  = (lane >> 4) << 4;

    auto stage = [&](int b, int koff) {
        int c0 = wave, c1 = wave + 4;
        int ra0 = c0 * 8 + srow, ra1 = c1 * 8 + srow;
        GLL(Ab + (size_t)ra0 * lda + koff + scol, &As[b][c0 * 512]);
        GLL(Ab + (size_t)ra1 * lda + koff + scol, &As[b][c1 * 512]);
        GLL(Wb + (size_t)ra0 * ldw + koff + scol, &Bs[b][c0 * 512]);
        GLL(Wb + (size_t)ra1 * ldw + koff + scol, &Bs[b][c1 * 512]);
    };

    stage(0, 0);
    int bq = 0;
    for (int it = 0; it < nk; ++it) {
        __syncthreads();
        if (it + 1 < nk) stage(bq ^ 1, (it + 1) << 6);
        const bf16* as = As[bq];
        const bf16* bs = Bs[bq];
#pragma unroll
        for (int k2 = 0; k2 < 2; ++k2) {
            const int co = (((k2 << 6) | kq) ^ swz) >> 1;
            bf16x8 a0 = *(const bf16x8*)&as[rA0 * 64 + co];
            bf16x8 a1 = *(const bf16x8*)&as[(rA0 + 16) * 64 + co];
            bf16x8 b0 = *(const bf16x8*)&bs[rB0 * 64 + co];
            bf16x8 b1 = *(const bf16x8*)&bs[(rB0 + 16) * 64 + co];
            acc[0] = MFMA(a0, b0, acc[0], 0, 0, 0);
            acc[1] = MFMA(a0, b1, acc[1], 0, 0, 0);
            acc[2] = MFMA(a1, b0, acc[2], 0, 0, 0);
            acc[3] = MFMA(a1, b1, acc[3], 0, 0, 0);
        }
        bq ^= 1;
    }
}

__device__ __forceinline__ void store64f(float* __restrict__ P, int bm, int bn,
                                         f32x4 (&acc)[4])
{
    const int lane = threadIdx.x & 63, wave = threadIdx.x >> 6;
    const int wr = wave & 1, wc = wave >> 1;
    const int ln = lane & 15, q = lane >> 4;
    const int row0 = bm + wr * 32 + q * 4;
    const int col0 = bn + wc * 32 + ln;
#pragma unroll
    for (int r = 0; r < 4; ++r) {
        P[(size_t)(row0 + r) * 4096 + col0]           = acc[0][r];
        P[(size_t)(row0 + r) * 4096 + col0 + 16]      = acc[1][r];
        P[(size_t)(row0 + 16 + r) * 4096 + col0]      = acc[2][r];
        P[(size_t)(row0 + 16 + r) * 4096 + col0 + 16] = acc[3][r];
    }
}

__device__ __forceinline__ void store64b(bf16* __restrict__ P, int bm, int bn,
                                         f32x4 (&acc)[4])
{
    const int lane = threadIdx.x & 63, wave = threadIdx.x >> 6;
    const int wr = wave & 1, wc = wave >> 1;
    const int ln = lane & 15, q = lane >> 4;
    const int row0 = bm + wr * 32 + q * 4;
    const int col0 = bn + wc * 32 + ln;
#pragma unroll
    for (int r = 0; r < 4; ++r) {
        P[(size_t)(row0 + r) * 4096 + col0]           = (bf16)acc[0][r];
        P[(size_t)(row0 + r) * 4096 + col0 + 16]      = (bf16)acc[1][r];
        P[(size_t)(row0 + 16 + r) * 4096 + col0]      = (bf16)acc[2][r];
        P[(size_t)(row0 + 16 + r) * 4096 + col0 + 16] = (bf16)acc[3][r];
    }
}

// split-K GEMM -> fp32 slices (prologue base). grid (64 nt, 2 mt, z)
__global__ __launch_bounds__(256) void gemm64_k(
    const bf16* __restrict__ A, int lda,
    const bf16* __restrict__ W, int ldw, int Kc,
    float* __restrict__ P)
{
    __shared__ bf16 As[2][4096], Bs[2][4096];
    const int nt = blockIdx.x, mt = blockIdx.y, zz = blockIdx.z;
    f32x4 acc[4];
#pragma unroll
    for (int i = 0; i < 4; ++i) acc[i] = (f32x4){0.f, 0.f, 0.f, 0.f};
    const bf16* Ab = A + (size_t)mt * 64 * lda + (size_t)zz * Kc;
    const bf16* Wb = W + (size_t)nt * 64 * ldw + (size_t)zz * Kc;
    core64(As, Bs, Ab, lda, Wb, ldw, Kc >> 6, acc);
    store64f(P + (size_t)zz * SLICE, mt * 64, nt * 64, acc);
}

// split-K GEMM -> bf16 slices (kA). grid (64 nt, 2 mt, z)
__global__ __launch_bounds__(256) void gemm64b_k(
    const bf16* __restrict__ A, int lda,
    const bf16* __restrict__ W, int ldw, int Kc,
    bf16* __restrict__ P)
{
    __shared__ bf16 As[2][4096], Bs[2][4096];
    const int nt = blockIdx.x, mt = blockIdx.y, zz = blockIdx.z;
    f32x4 acc[4];
#pragma unroll
    for (int i = 0; i < 4; ++i) acc[i] = (f32x4){0.f, 0.f, 0.f, 0.f};
    const bf16* Ab = A + (size_t)mt * 64 * lda + (size_t)zz * Kc;
    const bf16* Wb = W + (size_t)nt * 64 * ldw + (size_t)zz * Kc;
    core64(As, Bs, Ab, lda, Wb, ldw, Kc >> 6, acc);
    store64b(P + (size_t)zz * SLICE, mt * 64, nt * 64, acc);
}

// ---------------------------------------------------------------------------
// kE: end-of-step combined GEMMs, all nk=8, bf16 slices (R12-proven).
// ---------------------------------------------------------------------------
__global__ __launch_bounds__(256) void kE_k(
    const bf16* __restrict__ hh,   const bf16* __restrict__ Wwr,
    const bf16* __restrict__ Wcat, const bf16* __restrict__ Wdh,
    bf16* __restrict__ wrP, bf16* __restrict__ encP, bf16* __restrict__ decP,
    int zoff)
{
    __shared__ bf16 As[2][4096], Bs[2][4096];
    const int nt = blockIdx.x, mt = blockIdx.y, zz = blockIdx.z + zoff;
    f32x4 acc[4];
#pragma unroll
    for (int i = 0; i < 4; ++i) acc[i] = (f32x4){0.f, 0.f, 0.f, 0.f};

    const bf16* Ab;
    const bf16* Wb;
    int ldw;
    bf16* P;
    if (zz < 2) {
        Ab = hh + (size_t)mt * 64 * 2048 + zz * 512;
        Wb = Wwr + (size_t)nt * 64 * 1024 + zz * 512;
        ldw = 1024; P = wrP + (size_t)zz * SLICE;
    } else if (zz < 6) {
        int s = zz - 2;
        Ab = hh + (size_t)mt * 64 * 2048 + s * 512;
        Wb = Wcat + (size_t)nt * 64 * 2048 + s * 512;
        ldw = 2048; P = encP + (size_t)(8 + s) * SLICE;
    } else {
        int g = zz - 6;
        Ab = hh + (size_t)mt * 64 * 2048 + g * 512;
        Wb = Wdh + (size_t)nt * 64 * 1024 + g * 512;
        ldw = 1024; P = decP + (size_t)g * SLICE;
    }
    core64(As, Bs, Ab, 2048, Wb, ldw, 8, acc);
    store64b(P, mt * 64, nt * 64, acc);
}

// ---------------------------------------------------------------------------
// consumers
// ---------------------------------------------------------------------------
// fin0: sum 8 fp32 slices + both enc biases -> base fp32. grid 512.
__global__ __launch_bounds__(256) void fin0_k(
    const float* __restrict__ P, float* __restrict__ base,
    const float* __restrict__ b1, const float* __restrict__ b2)
{
    const int i = blockIdx.x * 256 + threadIdx.x;
    const int row = i >> 10, j = i & 1023;
    const size_t off = (size_t)row * 4096 + (j << 2);
    float s0 = 0.f, s1 = 0.f, s2 = 0.f, s3 = 0.f;
#pragma unroll
    for (int z = 0; z < 8; ++z) {
        float4 p = *(const float4*)(P + (size_t)z * SLICE + off);
        s0 += p.x; s1 += p.y; s2 += p.z; s3 += p.w;
    }
    base[off + 0] = s0 + b1[j]        + b2[j];
    base[off + 1] = s1 + b1[1024 + j] + b2[1024 + j];
    base[off + 2] = s2 + b1[2048 + j] + b2[2048 + j];
    base[off + 3] = s3 + b1[3072 + j] + b2[3072 + j];
}

// kB: sum encP bf16 slices 0-11 (x8 vectorized) + base -> enc LSTM -> henc.
__global__ __launch_bounds__(256) void kB_k(
    const bf16* __restrict__ encP, const float* __restrict__ base,
    float* __restrict__ c_enc, bf16* __restrict__ hh)
{
    const int i = blockIdx.x * 256 + threadIdx.x;   // 0..65535
    const int row = i >> 9, li = i & 511;
    const size_t off = (size_t)row * 4096 + (li << 3);
    float s[8] = {0.f, 0.f, 0.f, 0.f, 0.f, 0.f, 0.f, 0.f};
#pragma unroll
    for (int z = 0; z < 12; ++z) {
        bf16x8 p = *(const bf16x8*)(encP + (size_t)z * SLICE + off);
#pragma unroll
        for (int k = 0; k < 8; ++k) s[k] += (float)p[k];
    }
    float4 bb0 = *(const float4*)(base + off);
    float4 bb1 = *(const float4*)(base + off + 4);
    const int j0 = li << 1;                          // gate-quad index
    {
        float gi = s[0] + bb0.x, gf = s[1] + bb0.y, gg = s[2] + bb0.z, go = s[3] + bb0.w;
        int ci = row * 1024 + j0;
        float cn = sigf(gf) * c_enc[ci] + sigf(gi) * tanhf(gg);
        c_enc[ci] = cn;
        hh[(size_t)row * 2048 + 1024 + j0] = (bf16)(sigf(go) * tanhf(cn));
    }
    {
        float gi = s[4] + bb1.x, gf = s[5] + bb1.y, gg = s[6] + bb1.z, go = s[7] + bb1.w;
        int ci = row * 1024 + j0 + 1;
        float cn = sigf(gf) * c_enc[ci] + sigf(gi) * tanhf(gg);
        c_enc[ci] = cn;
        hh[(size_t)row * 2048 + 1024 + j0 + 1] = (bf16)(sigf(go) * tanhf(cn));
    }
}

// kF: c_t += wrP0+wrP1 (bf16) + b_wr -> negs; optional out
__global__ __launch_bounds__(256) void kF_k(
    const bf16* __restrict__ wrP, const float* __restrict__ b_wr,
    float* __restrict__ c_t, bf16* __restrict__ negs, float* __restrict__ outp)
{
    const int qi = blockIdx.x * 256 + threadIdx.x;
    const int row = qi >> 10, cq = qi & 1023;
    const size_t off = (size_t)row * 4096 + (cq << 2);
    bf16x4 p0 = *(const bf16x4*)(wrP + off);
    bf16x4 p1 = *(const bf16x4*)(wrP + SLICE + off);
    float4 cv = *(const float4*)(c_t + off);
    float4 bw = *(const float4*)(b_wr + (cq << 2));
    float v0 = cv.x + (float)p0[0] + (float)p1[0] + bw.x;
    float v1 = cv.y + (float)p0[1] + (float)p1[1] + bw.y;
    float v2 = cv.z + (float)p0[2] + (float)p1[2] + bw.z;
    float v3 = cv.w + (float)p0[3] + (float)p1[3] + bw.w;
    *(float4*)(c_t + off) = make_float4(v0, v1, v2, v3);
    negs[off + 0] = (bf16)(-sigf(v0));
    negs[off + 1] = (bf16)(-sigf(v1));
    negs[off + 2] = (bf16)(-sigf(v2));
    negs[off + 3] = (bf16)(-sigf(v3));
    if (outp)
        *(float4*)(outp + off) = make_float4(sigf(v0), sigf(v1), sigf(v2), sigf(v3));
}

// ---------------------------------------------------------------------------
// kC: mu/sigma GEMM (128x32 tile, K=1024 as 4x256) + reparam -> zbf. grid 16.
// ---------------------------------------------------------------------------
struct SmemG32 {
    bf16 As[4][128][64];   // 64 KB
    bf16 Ws[4][32][64];    // 16 KB
};

__global__ __launch_bounds__(256) void kC_k(
    const bf16* __restrict__ hh, const bf16* __restrict__ Wms,
    const float* __restrict__ b_mu, const float* __restrict__ b_sig,
    const float* __restrict__ eps_t, bf16* __restrict__ zbf)
{
    __shared__ SmemG32 sm;
    const int nt = blockIdx.x;
    const int tid = threadIdx.x, lane = tid & 63, wave = tid >> 6;
    const int srow = lane >> 3, scol = ((lane & 7) ^ srow) << 3;
    const int ln = lane & 15, kq = (lane >> 4) << 4;
    const int swz = (lane & 7) << 4;
    const int rA = wave * 32 + ln;
    const bf16* Wb = Wms + (size_t)nt * 32 * 1024;
    const bf16* Ab = hh + 1024;

    f32x4 acc[2][2];
#pragma unroll
    for (int m = 0; m < 2; ++m)
#pragma unroll
        for (int n = 0; n < 2; ++n) acc[m][n] = (f32x4){0.f, 0.f, 0.f, 0.f};

    for (int it = 0; it < 4; ++it) {
        if (it) __syncthreads();
        const int koff = it * 256;
#pragma unroll
        for (int kc = 0; kc < 4; ++kc) {
            const int kg = koff + kc * 64 + scol;
#pragma unroll
            for (int i = 0; i < 4; ++i) {
                int rb = i * 32 + wave * 8;
                GLL(Ab + (size_t)(rb + srow) * 2048 + kg, &sm.As[kc][rb][0]);
            }
            GLL(Wb + (size_t)(wave * 8 + srow) * 1024 + kg, &sm.Ws[kc][wave * 8][0]);
        }
        __syncthreads();
#pragma unroll
        for (int kc = 0; kc < 4; ++kc)
#pragma unroll
            for (int k2 = 0; k2 < 2; ++k2) {
                const int co = (((k2 << 6) | kq) ^ swz) >> 1;
                bf16x8 a0 = *(const bf16x8*)&sm.As[kc][rA][co];
                bf16x8 a1 = *(const bf16x8*)&sm.As[kc][rA + 16][co];
                bf16x8 b0 = *(const bf16x8*)&sm.Ws[kc][ln][co];
                bf16x8 b1 = *(const bf16x8*)&sm.Ws[kc][ln + 16][co];
                acc[0][0] = MFMA(a0, b0, acc[0][0], 0, 0, 0);
                acc[0][1] = MFMA(a0, b1, acc[0][1], 0, 0, 0);
                acc[1][0] = MFMA(a1, b0, acc[1][0], 0, 0, 0);
                acc[1][1] = MFMA(a1, b1, acc[1][1], 0, 0, 0);
            }
    }
    __syncthreads();

    float* Cl = (float*)&sm;
    const int q = lane >> 4;
#pragma unroll
    for (int f = 0; f < 2; ++f)
#pragma unroll
        for (int n = 0; n < 2; ++n)
#pragma unroll
            for (int r = 0; r < 4; ++r)
                Cl[(wave * 32 + f * 16 + q * 4 + r) * 33 + n * 16 + ln] = acc[f][n][r];
    __syncthreads();

#pragma unroll
    for (int it = 0; it < 8; ++it) {
        int li = it * 256 + tid;
        int row = li >> 4, zl = li & 15;
        int zi = nt * 16 + zl;
        float mu = Cl[row * 33 + zl * 2]     + b_mu[zi];
        float ls = Cl[row * 33 + zl * 2 + 1] + b_sig[zi];
        float z = eps_t[row * 256 + zi] * expf(ls) + mu;
        zbf[(size_t)row * 256 + zi] = (bf16)z;
    }
}

// ---------------------------------------------------------------------------
// kD: dec z-GEMM (64x64 tile, K=256 one-shot via core64) + gdhh slices +
// biases + LSTM -> hdec (hh[j]). grid 128, 32 KB LDS.
// ---------------------------------------------------------------------------
struct SmemK { bf16 A[2][4096]; bf16 B[2][4096]; };   // 32 KB

__global__ __launch_bounds__(256) void kD_k(
    const bf16* __restrict__ zbf, const bf16* __restrict__ Wdz,
    const bf16* __restrict__ decP,
    const float* __restrict__ b_ihd, const float* __restrict__ b_hhd,
    float* __restrict__ c_dec, bf16* __restrict__ hh)
{
    __shared__ SmemK sm;
    const int bid = blockIdx.x;
    const int mt = bid & 1, nt = bid >> 1;      // rows mt*64, cols(n') nt*64
    const int tid = threadIdx.x, lane = tid & 63, wave = tid >> 6;
    const int wr = wave & 1, wc = wave >> 1;
    const int ln = lane & 15, q = lane >> 4;

    const bf16* Ab = zbf + (size_t)mt * 64 * 256;
    const bf16* Wb = Wdz + (size_t)nt * 64 * 256;
    f32x4 acc[4];
#pragma unroll
    for (int i = 0; i < 4; ++i) acc[i] = (f32x4){0.f, 0.f, 0.f, 0.f};
    core64(sm.A, sm.B, Ab, 256, Wb, 256, 4, acc);

    __syncthreads();
    float* Cl = (float*)&sm;                     // 64 x 66 fp32 (16.9 KB)
    const int r0 = wr * 32 + q * 4;
    const int c0 = wc * 32 + ln;
#pragma unroll
    for (int r = 0; r < 4; ++r) {
        Cl[(r0 + r) * 66 + c0]           = acc[0][r];
        Cl[(r0 + r) * 66 + c0 + 16]      = acc[1][r];
        Cl[(r0 + 16 + r) * 66 + c0]      = acc[2][r];
        Cl[(r0 + 16 + r) * 66 + c0 + 16] = acc[3][r];
    }
    __syncthreads();

#pragma unroll
    for (int it = 0; it < 4; ++it) {
        int li = it * 256 + tid;                 // 0..1023
        int lrow = li >> 4, jl = li & 15;
        int row = mt * 64 + lrow;
        int np0 = nt * 64 + jl * 4;
        int J = np0 >> 2;
        const float* cr = &Cl[lrow * 66 + jl * 4];
        const bf16* gp = decP + (size_t)row * 4096 + np0;
        bf16x4 g0v = *(const bf16x4*)gp;
        bf16x4 g1v = *(const bf16x4*)(gp + SLICE);
        float gi = cr[0] + (float)g0v[0] + (float)g1v[0] + b_ihd[J]        + b_hhd[J];
        float gf = cr[1] + (float)g0v[1] + (float)g1v[1] + b_ihd[1024 + J] + b_hhd[1024 + J];
        float gg = cr[2] + (float)g0v[2] + (float)g1v[2] + b_ihd[2048 + J] + b_hhd[2048 + J];
        float go = cr[3] + (float)g0v[3] + (float)g1v[3] + b_ihd[3072 + J] + b_hhd[3072 + J];
        int ci = row * 1024 + J;
        float cn = sigf(gf) * c_dec[ci] + sigf(gi) * tanhf(gg);
        c_dec[ci] = cn;
        hh[(size_t)row * 2048 + J] = (bf16)(sigf(go) * tanhf(cn));
    }
}

// ---------------- merged prologue: init + all weight packing ----------------
#define PBL (B_ * 4096)
#define PBH (B_ * 1024)

__device__ __forceinline__ bf16x8 cvt8(const float* s) {
    float4 a = *(const float4*)s, b = *(const float4*)(s + 4);
    bf16x8 v = { (bf16)a.x, (bf16)a.y, (bf16)a.z, (bf16)a.w,
                 (bf16)b.x, (bf16)b.y, (bf16)b.z, (bf16)b.w };
    return v;
}

__device__ __forceinline__ void st_nt(bf16* p, bf16x8 v) {
    __builtin_nontemporal_store(v, (bf16x8*)p);
}

// 2 units per thread. roles by bid:
// [0,6144) conv_es | +1280 conv_dec | +128 conv_ms | +1024 conv_wr | +1024 init
__global__ __launch_bounds__(256) void prolog_k(
    const float* __restrict__ x, const float* __restrict__ c0,
    const float* __restrict__ h0e, const float* __restrict__ h0d,
    const float* __restrict__ Wih_e, const float* __restrict__ Whh_e,
    const float* __restrict__ Wih_d, const float* __restrict__ Whh_d,
    const float* __restrict__ Wmu, const float* __restrict__ Wsig,
    const float* __restrict__ Wwr_f,
    float* __restrict__ c_t, float* __restrict__ c_enc, float* __restrict__ c_dec,
    bf16* __restrict__ negs, bf16* __restrict__ hh, bf16* __restrict__ x_bf,
    bf16* __restrict__ wxh, bf16* __restrict__ wsum, bf16* __restrict__ wcat,
    bf16* __restrict__ wdz, bf16* __restrict__ wdh, bf16* __restrict__ wms,
    bf16* __restrict__ wwr)
{
    const int bid = blockIdx.x;
    if (bid < 6144) {
#pragma unroll
        for (int u = 0; u < 2; ++u) {
            int id = (bid * 256 + threadIdx.x) * 2 + u;
            int np = id / 768, c = (id - np * 768) * 8;
            int n = ((np & 3) << 10) + (np >> 2);
            if (c < 4096) {
                const float* sx = Wih_e + (size_t)n * 9216 + c;
                const float* sh = sx + 4096;
                float4 a = *(const float4*)sh, b = *(const float4*)(sh + 4);
                float4 e = *(const float4*)sx, f = *(const float4*)(sx + 4);
                bf16x8 vh = { (bf16)a.x, (bf16)a.y, (bf16)a.z, (bf16)a.w,
                              (bf16)b.x, (bf16)b.y, (bf16)b.z, (bf16)b.w };
                bf16x8 vs = { (bf16)(a.x + e.x), (bf16)(a.y + e.y), (bf16)(a.z + e.z), (bf16)(a.w + e.w),
                              (bf16)(b.x + f.x), (bf16)(b.y + f.y), (bf16)(b.z + f.z), (bf16)(b.w + f.w) };
                st_nt(wxh  + (size_t)np * 4096 + c, vh);
                st_nt(wsum + (size_t)np * 4096 + c, vs);
            } else if (c < 5120) {
                st_nt(wcat + (size_t)np * 2048 + (c - 4096),
                      cvt8(Wih_e + (size_t)n * 9216 + 8192 + (c - 4096)));
            } else {
                st_nt(wcat + (size_t)np * 2048 + 1024 + (c - 5120),
                      cvt8(Whh_e + (size_t)n * 1024 + (c - 5120)));
            }
        }
        return;
    }
    if (bid < 6144 + 1280) {
#pragma unroll
        for (int u = 0; u < 2; ++u) {
            int id = ((bid - 6144) * 256 + threadIdx.x) * 2 + u;
            int np = id / 160, c = (id - np * 160) * 8;
            int n = ((np & 3) << 10) + (np >> 2);
            if (c < 256)
                st_nt(wdz + (size_t)np * 256 + c, cvt8(Wih_d + (size_t)n * 256 + c));
            else
                st_nt(wdh + (size_t)np * 1024 + (c - 256),
                      cvt8(Whh_d + (size_t)n * 1024 + (c - 256)));
        }
        return;
    }
    if (bid < 6144 + 1280 + 128) {
#pragma unroll
        for (int u = 0; u < 2; ++u) {
            int id = ((bid - 6144 - 1280) * 256 + threadIdx.x) * 2 + u;
            int np = id >> 7, c = (id & 127) * 8;
            int zi = np >> 1;
            const float* src = ((np & 1) ? Wsig : Wmu) + (size_t)zi * 1024 + c;
            st_nt(wms + (size_t)np * 1024 + c, cvt8(src));
        }
        return;
    }
    if (bid < 6144 + 1280 + 128 + 1024) {
#pragma unroll
        for (int u = 0; u < 2; ++u) {
            int id = ((bid - 6144 - 1280 - 128) * 256 + threadIdx.x) * 2 + u;
            st_nt(wwr + (size_t)id * 8, cvt8(Wwr_f + (size_t)id * 8));
        }
        return;
    }
    // init role
#pragma unroll
    for (int u = 0; u < 2; ++u) {
        int i = ((bid - 6144 - 1280 - 128 - 1024) * 256 + threadIdx.x) * 2 + u;
        int n = i & 4095;
        float c = c0[n];
        c_t[i] = c;
        negs[i] = (bf16)(-sigf(c));
        x_bf[i] = (bf16)x[i];
        if (i < PBH) {
            int row = i >> 10, j = i & 1023;
            c_enc[i] = 0.f;
            c_dec[i] = 0.f;
            hh[(size_t)row * 2048 + j]        = (bf16)h0d[j];
            hh[(size_t)row * 2048 + 1024 + j] = (bf16)h0e[j];
        }
    }
}

// ---------------- launch ----------------
extern "C" void kernel_launch(void* const* d_in, const int* in_sizes, int n_in,
                              void* d_out, int out_size, void* d_ws, size_t ws_size,
                              hipStream_t stream) {
    const float* x      = (const float*)d_in[0];
    const float* eps    = (const float*)d_in[1];
    const float* c0     = (const float*)d_in[2];
    const float* h0e    = (const float*)d_in[3];
    const float* h0d    = (const float*)d_in[4];
    const float* W_ih_e = (const float*)d_in[5];
    const float* b_ih_e = (const float*)d_in[6];
    const float* W_hh_e = (const float*)d_in[7];
    const float* b_hh_e = (const float*)d_in[8];
    const float* W_mu   = (const float*)d_in[9];
    const float* b_mu   = (const float*)d_in[10];
    const float* W_sig  = (const float*)d_in[11];
    const float* b_sig  = (const float*)d_in[12];
    const float* W_ih_d = (const float*)d_in[13];
    const float* b_ih_d = (const float*)d_in[14];
    const float* W_hh_d = (const float*)d_in[15];
    const float* b_hh_d = (const float*)d_in[16];
    const float* W_wr   = (const float*)d_in[17];
    const float* b_wr   = (const float*)d_in[18];
    float* out = (float*)d_out;

    float* f = (float*)d_ws;
    float* c_t   = f; f += SLICE;
    float* base  = f; f += SLICE;
    float* pP    = f; f += (size_t)8 * SLICE;    // fp32 prologue partials (z=8)
    float* c_enc = f; f += 131072;
    float* c_dec = f; f += 131072;
    bf16* bp    = (bf16*)f;
    bf16* encP  = bp; bp += (size_t)12 * SLICE;  // 0-7: kA; 8-11: hdhe
    bf16* decP  = bp; bp += (size_t)2 * SLICE;   // gdhh slices
    bf16* wrP   = bp; bp += (size_t)2 * SLICE;
    bf16* negs  = bp; bp += (size_t)B_ * 4096;
    bf16* hh    = bp; bp += (size_t)B_ * 2048;   // [hdec | henc] per row
    bf16* zbf   = bp; bp += (size_t)B_ * 256;
    bf16* x_bf  = bp; bp += (size_t)B_ * 4096;
    bf16* Wxh   = bp; bp += (size_t)4096 * 4096;
    bf16* Wsum  = bp; bp += (size_t)4096 * 4096;
    bf16* Wcat  = bp; bp += (size_t)4096 * 2048;
    bf16* Wdz   = bp; bp += (size_t)4096 * 256;
    bf16* Wdh   = bp; bp += (size_t)4096 * 1024;
    bf16* Wms   = bp; bp += (size_t)512 * 1024;
    bf16* Wwr   = bp; bp += (size_t)4096 * 1024;

    dim3 blk(256);

    // merged prologue: init + all weight packing (2 units/thread, NT stores)
    prolog_k<<<dim3(9600), blk, 0, stream>>>(
        x, c0, h0e, h0d, W_ih_e, W_hh_e, W_ih_d, W_hh_d, W_mu, W_sig, W_wr,
        c_t, c_enc, c_dec, negs, hh, x_bf,
        Wxh, Wsum, Wcat, Wdz, Wdh, Wms, Wwr);

    // base = b_ih_e + b_hh_e + x @ Wsum^T  (gate-interleaved cols), fp32 z=8
    gemm64_k<<<dim3(64, 2, 8), blk, 0, stream>>>(x_bf, 4096, Wsum, 4096, 512, pP);
    fin0_k<<<dim3(512), blk, 0, stream>>>(pP, base, b_ih_e, b_hh_e);

    // preloop: hdhe (encP 8-11) + gdhh (decP 0-1) from initial hh
    kE_k<<<dim3(64, 2, 6), blk, 0, stream>>>(hh, Wwr, Wcat, Wdh, wrP, encP, decP, 2);

    for (int t = 0; t < T_; ++t) {
        // kA: negs @ Wxh^T (K=4096), z=8, Kc=512 -> encP slices 0-7
        gemm64b_k<<<dim3(64, 2, 8), blk, 0, stream>>>(negs, 4096, Wxh, 4096, 512, encP);
        // kB: sum 12 slices + base -> enc LSTM -> henc
        kB_k<<<dim3(256), blk, 0, stream>>>(encP, base, c_enc, hh);
        // kC: mu/sigma + reparam -> zbf
        kC_k<<<dim3(16), blk, 0, stream>>>(hh, Wms, b_mu, b_sig,
                                           eps + (size_t)t * (B_ * 256), zbf);
        // kD: dec z-GEMM + gdhh slices + LSTM -> hdec
        kD_k<<<dim3(128), blk, 0, stream>>>(zbf, Wdz, decP, b_ih_d, b_hh_d, c_dec, hh);
        // kE: wr (z=2) + hdhe (z=4) + gdhh (z=2), all nk=8
        kE_k<<<dim3(64, 2, 8), blk, 0, stream>>>(hh, Wwr, Wcat, Wdh, wrP, encP, decP, 0);
        // kF: c_t += wr + b_wr -> negs (+ out at last step)
        kF_k<<<dim3(512), blk, 0, stream>>>(wrP, b_wr, c_t, negs,
                                            (t == T_ - 1) ? out : nullptr);
    }
}

// Round 18
// 811.740 us; speedup vs baseline: 1.0257x; 1.0257x over previous
//
#include <hip/hip_runtime.h>

#define B_   128
#define T_   16

typedef __bf16 bf16;
typedef __bf16 bf16x4 __attribute__((ext_vector_type(4)));
typedef __bf16 bf16x8 __attribute__((ext_vector_type(8)));
typedef float f32x4 __attribute__((ext_vector_type(4)));

#define GLL(SRC, DST) __builtin_amdgcn_global_load_lds( \
    (const __attribute__((address_space(1))) void*)(SRC), \
    (__attribute__((address_space(3))) void*)(DST), 16, 0, 0)

#define MFMA __builtin_amdgcn_mfma_f32_16x16x32_bf16
#define SLICE 524288   // 128*4096 elements per partial slice

__device__ __forceinline__ float sigf(float x) { return 1.f / (1.f + expf(-x)); }

// ---------------------------------------------------------------------------
// R2/R10-proven 64x64-tile GEMM core: BK=64, dbuf 32KB LDS, 4 waves x 32x32.
// ---------------------------------------------------------------------------
__device__ __forceinline__ void core64(
    bf16 (&As)[2][4096], bf16 (&Bs)[2][4096],
    const bf16* __restrict__ Ab, int lda,
    const bf16* __restrict__ Wb, int ldw,
    int nk, f32x4 (&acc)[4])
{
    const int tid = threadIdx.x, lane = tid & 63, wave = tid >> 6;
    const int srow = lane >> 3;
    const int scol = ((lane & 7) ^ srow) << 3;     // pre-swizzled source col
    const int wr = wave & 1, wc = wave >> 1;
    const int ln = lane & 15;
    const int rA0 = wr * 32 + ln;
    const int rB0 = wc * 32 + ln;
    const int swz = (lane & 7) << 4;
    const int kq  = (lane >> 4) << 4;

    auto stage = [&](int b, int koff) {
        int c0 = wave, c1 = wave + 4;
        int ra0 = c0 * 8 + srow, ra1 = c1 * 8 + srow;
        GLL(Ab + (size_t)ra0 * lda + koff + scol, &As[b][c0 * 512]);
        GLL(Ab + (size_t)ra1 * lda + koff + scol, &As[b][c1 * 512]);
        GLL(Wb + (size_t)ra0 * ldw + koff + scol, &Bs[b][c0 * 512]);
        GLL(Wb + (size_t)ra1 * ldw + koff + scol, &Bs[b][c1 * 512]);
    };

    stage(0, 0);
    int bq = 0;
    for (int it = 0; it < nk; ++it) {
        __syncthreads();
        if (it + 1 < nk) stage(bq ^ 1, (it + 1) << 6);
        const bf16* as = As[bq];
        const bf16* bs = Bs[bq];
#pragma unroll
        for (int k2 = 0; k2 < 2; ++k2) {
            const int co = (((k2 << 6) | kq) ^ swz) >> 1;
            bf16x8 a0 = *(const bf16x8*)&as[rA0 * 64 + co];
            bf16x8 a1 = *(const bf16x8*)&as[(rA0 + 16) * 64 + co];
            bf16x8 b0 = *(const bf16x8*)&bs[rB0 * 64 + co];
            bf16x8 b1 = *(const bf16x8*)&bs[(rB0 + 16) * 64 + co];
            acc[0] = MFMA(a0, b0, acc[0], 0, 0, 0);
            acc[1] = MFMA(a0, b1, acc[1], 0, 0, 0);
            acc[2] = MFMA(a1, b0, acc[2], 0, 0, 0);
            acc[3] = MFMA(a1, b1, acc[3], 0, 0, 0);
        }
        bq ^= 1;
    }
}

__device__ __forceinline__ void store64f(float* __restrict__ P, int bm, int bn,
                                         f32x4 (&acc)[4])
{
    const int lane = threadIdx.x & 63, wave = threadIdx.x >> 6;
    const int wr = wave & 1, wc = wave >> 1;
    const int ln = lane & 15, q = lane >> 4;
    const int row0 = bm + wr * 32 + q * 4;
    const int col0 = bn + wc * 32 + ln;
#pragma unroll
    for (int r = 0; r < 4; ++r) {
        P[(size_t)(row0 + r) * 4096 + col0]           = acc[0][r];
        P[(size_t)(row0 + r) * 4096 + col0 + 16]      = acc[1][r];
        P[(size_t)(row0 + 16 + r) * 4096 + col0]      = acc[2][r];
        P[(size_t)(row0 + 16 + r) * 4096 + col0 + 16] = acc[3][r];
    }
}

__device__ __forceinline__ void store64b(bf16* __restrict__ P, int bm, int bn,
                                         f32x4 (&acc)[4])
{
    const int lane = threadIdx.x & 63, wave = threadIdx.x >> 6;
    const int wr = wave & 1, wc = wave >> 1;
    const int ln = lane & 15, q = lane >> 4;
    const int row0 = bm + wr * 32 + q * 4;
    const int col0 = bn + wc * 32 + ln;
#pragma unroll
    for (int r = 0; r < 4; ++r) {
        P[(size_t)(row0 + r) * 4096 + col0]           = (bf16)acc[0][r];
        P[(size_t)(row0 + r) * 4096 + col0 + 16]      = (bf16)acc[1][r];
        P[(size_t)(row0 + 16 + r) * 4096 + col0]      = (bf16)acc[2][r];
        P[(size_t)(row0 + 16 + r) * 4096 + col0 + 16] = (bf16)acc[3][r];
    }
}

// split-K GEMM -> fp32 slices (prologue base). grid (64 nt, 2 mt, z)
__global__ __launch_bounds__(256) void gemm64_k(
    const bf16* __restrict__ A, int lda,
    const bf16* __restrict__ W, int ldw, int Kc,
    float* __restrict__ P)
{
    __shared__ bf16 As[2][4096], Bs[2][4096];
    const int nt = blockIdx.x, mt = blockIdx.y, zz = blockIdx.z;
    f32x4 acc[4];
#pragma unroll
    for (int i = 0; i < 4; ++i) acc[i] = (f32x4){0.f, 0.f, 0.f, 0.f};
    const bf16* Ab = A + (size_t)mt * 64 * lda + (size_t)zz * Kc;
    const bf16* Wb = W + (size_t)nt * 64 * ldw + (size_t)zz * Kc;
    core64(As, Bs, Ab, lda, Wb, ldw, Kc >> 6, acc);
    store64f(P + (size_t)zz * SLICE, mt * 64, nt * 64, acc);
}

// split-K GEMM -> bf16 slices (kA). grid (64 nt, 2 mt, z)
__global__ __launch_bounds__(256) void gemm64b_k(
    const bf16* __restrict__ A, int lda,
    const bf16* __restrict__ W, int ldw, int Kc,
    bf16* __restrict__ P)
{
    __shared__ bf16 As[2][4096], Bs[2][4096];
    const int nt = blockIdx.x, mt = blockIdx.y, zz = blockIdx.z;
    f32x4 acc[4];
#pragma unroll
    for (int i = 0; i < 4; ++i) acc[i] = (f32x4){0.f, 0.f, 0.f, 0.f};
    const bf16* Ab = A + (size_t)mt * 64 * lda + (size_t)zz * Kc;
    const bf16* Wb = W + (size_t)nt * 64 * ldw + (size_t)zz * Kc;
    core64(As, Bs, Ab, lda, Wb, ldw, Kc >> 6, acc);
    store64b(P + (size_t)zz * SLICE, mt * 64, nt * 64, acc);
}

// ---------------------------------------------------------------------------
// kE: end-of-step combined GEMMs, all nk=8, bf16 slices (R12-proven).
// ---------------------------------------------------------------------------
__global__ __launch_bounds__(256) void kE_k(
    const bf16* __restrict__ hh,   const bf16* __restrict__ Wwr,
    const bf16* __restrict__ Wcat, const bf16* __restrict__ Wdh,
    bf16* __restrict__ wrP, bf16* __restrict__ encP, bf16* __restrict__ decP,
    int zoff)
{
    __shared__ bf16 As[2][4096], Bs[2][4096];
    const int nt = blockIdx.x, mt = blockIdx.y, zz = blockIdx.z + zoff;
    f32x4 acc[4];
#pragma unroll
    for (int i = 0; i < 4; ++i) acc[i] = (f32x4){0.f, 0.f, 0.f, 0.f};

    const bf16* Ab;
    const bf16* Wb;
    int ldw;
    bf16* P;
    if (zz < 2) {
        Ab = hh + (size_t)mt * 64 * 2048 + zz * 512;
        Wb = Wwr + (size_t)nt * 64 * 1024 + zz * 512;
        ldw = 1024; P = wrP + (size_t)zz * SLICE;
    } else if (zz < 6) {
        int s = zz - 2;
        Ab = hh + (size_t)mt * 64 * 2048 + s * 512;
        Wb = Wcat + (size_t)nt * 64 * 2048 + s * 512;
        ldw = 2048; P = encP + (size_t)(8 + s) * SLICE;
    } else {
        int g = zz - 6;
        Ab = hh + (size_t)mt * 64 * 2048 + g * 512;
        Wb = Wdh + (size_t)nt * 64 * 1024 + g * 512;
        ldw = 1024; P = decP + (size_t)g * SLICE;
    }
    core64(As, Bs, Ab, 2048, Wb, ldw, 8, acc);
    store64b(P, mt * 64, nt * 64, acc);
}

// ---------------------------------------------------------------------------
// consumers
// ---------------------------------------------------------------------------
// fin0: sum 8 fp32 slices + both enc biases -> base fp32. grid 512.
__global__ __launch_bounds__(256) void fin0_k(
    const float* __restrict__ P, float* __restrict__ base,
    const float* __restrict__ b1, const float* __restrict__ b2)
{
    const int i = blockIdx.x * 256 + threadIdx.x;
    const int row = i >> 10, j = i & 1023;
    const size_t off = (size_t)row * 4096 + (j << 2);
    float s0 = 0.f, s1 = 0.f, s2 = 0.f, s3 = 0.f;
#pragma unroll
    for (int z = 0; z < 8; ++z) {
        float4 p = *(const float4*)(P + (size_t)z * SLICE + off);
        s0 += p.x; s1 += p.y; s2 += p.z; s3 += p.w;
    }
    base[off + 0] = s0 + b1[j]        + b2[j];
    base[off + 1] = s1 + b1[1024 + j] + b2[1024 + j];
    base[off + 2] = s2 + b1[2048 + j] + b2[2048 + j];
    base[off + 3] = s3 + b1[3072 + j] + b2[3072 + j];
}

// kB: sum encP bf16 slices 0-11 (x8 vectorized) + base -> enc LSTM -> henc.
__global__ __launch_bounds__(256) void kB_k(
    const bf16* __restrict__ encP, const float* __restrict__ base,
    float* __restrict__ c_enc, bf16* __restrict__ hh)
{
    const int i = blockIdx.x * 256 + threadIdx.x;   // 0..65535
    const int row = i >> 9, li = i & 511;
    const size_t off = (size_t)row * 4096 + (li << 3);
    float s[8] = {0.f, 0.f, 0.f, 0.f, 0.f, 0.f, 0.f, 0.f};
#pragma unroll
    for (int z = 0; z < 12; ++z) {
        bf16x8 p = *(const bf16x8*)(encP + (size_t)z * SLICE + off);
#pragma unroll
        for (int k = 0; k < 8; ++k) s[k] += (float)p[k];
    }
    float4 bb0 = *(const float4*)(base + off);
    float4 bb1 = *(const float4*)(base + off + 4);
    const int j0 = li << 1;                          // gate-quad index
    {
        float gi = s[0] + bb0.x, gf = s[1] + bb0.y, gg = s[2] + bb0.z, go = s[3] + bb0.w;
        int ci = row * 1024 + j0;
        float cn = sigf(gf) * c_enc[ci] + sigf(gi) * tanhf(gg);
        c_enc[ci] = cn;
        hh[(size_t)row * 2048 + 1024 + j0] = (bf16)(sigf(go) * tanhf(cn));
    }
    {
        float gi = s[4] + bb1.x, gf = s[5] + bb1.y, gg = s[6] + bb1.z, go = s[7] + bb1.w;
        int ci = row * 1024 + j0 + 1;
        float cn = sigf(gf) * c_enc[ci] + sigf(gi) * tanhf(gg);
        c_enc[ci] = cn;
        hh[(size_t)row * 2048 + 1024 + j0 + 1] = (bf16)(sigf(go) * tanhf(cn));
    }
}

// kF: c_t += wrP0+wrP1 (bf16) + b_wr -> negs; optional out
__global__ __launch_bounds__(256) void kF_k(
    const bf16* __restrict__ wrP, const float* __restrict__ b_wr,
    float* __restrict__ c_t, bf16* __restrict__ negs, float* __restrict__ outp)
{
    const int qi = blockIdx.x * 256 + threadIdx.x;
    const int row = qi >> 10, cq = qi & 1023;
    const size_t off = (size_t)row * 4096 + (cq << 2);
    bf16x4 p0 = *(const bf16x4*)(wrP + off);
    bf16x4 p1 = *(const bf16x4*)(wrP + SLICE + off);
    float4 cv = *(const float4*)(c_t + off);
    float4 bw = *(const float4*)(b_wr + (cq << 2));
    float v0 = cv.x + (float)p0[0] + (float)p1[0] + bw.x;
    float v1 = cv.y + (float)p0[1] + (float)p1[1] + bw.y;
    float v2 = cv.z + (float)p0[2] + (float)p1[2] + bw.z;
    float v3 = cv.w + (float)p0[3] + (float)p1[3] + bw.w;
    *(float4*)(c_t + off) = make_float4(v0, v1, v2, v3);
    negs[off + 0] = (bf16)(-sigf(v0));
    negs[off + 1] = (bf16)(-sigf(v1));
    negs[off + 2] = (bf16)(-sigf(v2));
    negs[off + 3] = (bf16)(-sigf(v3));
    if (outp)
        *(float4*)(outp + off) = make_float4(sigf(v0), sigf(v1), sigf(v2), sigf(v3));
}

// ---------------------------------------------------------------------------
// kC: mu/sigma GEMM (128x32 tile, K=1024 as 4x256) + reparam -> zbf. grid 16.
// ---------------------------------------------------------------------------
struct SmemG32 {
    bf16 As[4][128][64];   // 64 KB
    bf16 Ws[4][32][64];    // 16 KB
};

__global__ __launch_bounds__(256) void kC_k(
    const bf16* __restrict__ hh, const bf16* __restrict__ Wms,
    const float* __restrict__ b_mu, const float* __restrict__ b_sig,
    const float* __restrict__ eps_t, bf16* __restrict__ zbf)
{
    __shared__ SmemG32 sm;
    const int nt = blockIdx.x;
    const int tid = threadIdx.x, lane = tid & 63, wave = tid >> 6;
    const int srow = lane >> 3, scol = ((lane & 7) ^ srow) << 3;
    const int ln = lane & 15, kq = (lane >> 4) << 4;
    const int swz = (lane & 7) << 4;
    const int rA = wave * 32 + ln;
    const bf16* Wb = Wms + (size_t)nt * 32 * 1024;
    const bf16* Ab = hh + 1024;

    f32x4 acc[2][2];
#pragma unroll
    for (int m = 0; m < 2; ++m)
#pragma unroll
        for (int n = 0; n < 2; ++n) acc[m][n] = (f32x4){0.f, 0.f, 0.f, 0.f};

    for (int it = 0; it < 4; ++it) {
        if (it) __syncthreads();
        const int koff = it * 256;
#pragma unroll
        for (int kc = 0; kc < 4; ++kc) {
            const int kg = koff + kc * 64 + scol;
#pragma unroll
            for (int i = 0; i < 4; ++i) {
                int rb = i * 32 + wave * 8;
                GLL(Ab + (size_t)(rb + srow) * 2048 + kg, &sm.As[kc][rb][0]);
            }
            GLL(Wb + (size_t)(wave * 8 + srow) * 1024 + kg, &sm.Ws[kc][wave * 8][0]);
        }
        __syncthreads();
#pragma unroll
        for (int kc = 0; kc < 4; ++kc)
#pragma unroll
            for (int k2 = 0; k2 < 2; ++k2) {
                const int co = (((k2 << 6) | kq) ^ swz) >> 1;
                bf16x8 a0 = *(const bf16x8*)&sm.As[kc][rA][co];
                bf16x8 a1 = *(const bf16x8*)&sm.As[kc][rA + 16][co];
                bf16x8 b0 = *(const bf16x8*)&sm.Ws[kc][ln][co];
                bf16x8 b1 = *(const bf16x8*)&sm.Ws[kc][ln + 16][co];
                acc[0][0] = MFMA(a0, b0, acc[0][0], 0, 0, 0);
                acc[0][1] = MFMA(a0, b1, acc[0][1], 0, 0, 0);
                acc[1][0] = MFMA(a1, b0, acc[1][0], 0, 0, 0);
                acc[1][1] = MFMA(a1, b1, acc[1][1], 0, 0, 0);
            }
    }
    __syncthreads();

    float* Cl = (float*)&sm;
    const int q = lane >> 4;
#pragma unroll
    for (int f = 0; f < 2; ++f)
#pragma unroll
        for (int n = 0; n < 2; ++n)
#pragma unroll
            for (int r = 0; r < 4; ++r)
                Cl[(wave * 32 + f * 16 + q * 4 + r) * 33 + n * 16 + ln] = acc[f][n][r];
    __syncthreads();

#pragma unroll
    for (int it = 0; it < 8; ++it) {
        int li = it * 256 + tid;
        int row = li >> 4, zl = li & 15;
        int zi = nt * 16 + zl;
        float mu = Cl[row * 33 + zl * 2]     + b_mu[zi];
        float ls = Cl[row * 33 + zl * 2 + 1] + b_sig[zi];
        float z = eps_t[row * 256 + zi] * expf(ls) + mu;
        zbf[(size_t)row * 256 + zi] = (bf16)z;
    }
}

// ---------------------------------------------------------------------------
// kD: dec z-GEMM (64x64 tile, K=256 one-shot via core64) + gdhh slices +
// biases + LSTM -> hdec (hh[j]). grid 128, 32 KB LDS.
// ---------------------------------------------------------------------------
struct SmemK { bf16 A[2][4096]; bf16 B[2][4096]; };   // 32 KB

__global__ __launch_bounds__(256) void kD_k(
    const bf16* __restrict__ zbf, const bf16* __restrict__ Wdz,
    const bf16* __restrict__ decP,
    const float* __restrict__ b_ihd, const float* __restrict__ b_hhd,
    float* __restrict__ c_dec, bf16* __restrict__ hh)
{
    __shared__ SmemK sm;
    const int bid = blockIdx.x;
    const int mt = bid & 1, nt = bid >> 1;      // rows mt*64, cols(n') nt*64
    const int tid = threadIdx.x, lane = tid & 63, wave = tid >> 6;
    const int wr = wave & 1, wc = wave >> 1;
    const int ln = lane & 15, q = lane >> 4;

    const bf16* Ab = zbf + (size_t)mt * 64 * 256;
    const bf16* Wb = Wdz + (size_t)nt * 64 * 256;
    f32x4 acc[4];
#pragma unroll
    for (int i = 0; i < 4; ++i) acc[i] = (f32x4){0.f, 0.f, 0.f, 0.f};
    core64(sm.A, sm.B, Ab, 256, Wb, 256, 4, acc);

    __syncthreads();
    float* Cl = (float*)&sm;                     // 64 x 66 fp32 (16.9 KB)
    const int r0 = wr * 32 + q * 4;
    const int c0 = wc * 32 + ln;
#pragma unroll
    for (int r = 0; r < 4; ++r) {
        Cl[(r0 + r) * 66 + c0]           = acc[0][r];
        Cl[(r0 + r) * 66 + c0 + 16]      = acc[1][r];
        Cl[(r0 + 16 + r) * 66 + c0]      = acc[2][r];
        Cl[(r0 + 16 + r) * 66 + c0 + 16] = acc[3][r];
    }
    __syncthreads();

#pragma unroll
    for (int it = 0; it < 4; ++it) {
        int li = it * 256 + tid;                 // 0..1023
        int lrow = li >> 4, jl = li & 15;
        int row = mt * 64 + lrow;
        int np0 = nt * 64 + jl * 4;
        int J = np0 >> 2;
        const float* cr = &Cl[lrow * 66 + jl * 4];
        const bf16* gp = decP + (size_t)row * 4096 + np0;
        bf16x4 g0v = *(const bf16x4*)gp;
        bf16x4 g1v = *(const bf16x4*)(gp + SLICE);
        float gi = cr[0] + (float)g0v[0] + (float)g1v[0] + b_ihd[J]        + b_hhd[J];
        float gf = cr[1] + (float)g0v[1] + (float)g1v[1] + b_ihd[1024 + J] + b_hhd[1024 + J];
        float gg = cr[2] + (float)g0v[2] + (float)g1v[2] + b_ihd[2048 + J] + b_hhd[2048 + J];
        float go = cr[3] + (float)g0v[3] + (float)g1v[3] + b_ihd[3072 + J] + b_hhd[3072 + J];
        int ci = row * 1024 + J;
        float cn = sigf(gf) * c_dec[ci] + sigf(gi) * tanhf(gg);
        c_dec[ci] = cn;
        hh[(size_t)row * 2048 + J] = (bf16)(sigf(go) * tanhf(cn));
    }
}

// ---------------- merged prologue: init + all weight packing ----------------
#define PBL (B_ * 4096)
#define PBH (B_ * 1024)

__device__ __forceinline__ bf16x8 cvt8(const float* s) {
    float4 a = *(const float4*)s, b = *(const float4*)(s + 4);
    bf16x8 v = { (bf16)a.x, (bf16)a.y, (bf16)a.z, (bf16)a.w,
                 (bf16)b.x, (bf16)b.y, (bf16)b.z, (bf16)b.w };
    return v;
}

// Grid-stride 4 units/thread, regular stores. Roles by bid:
// [0,3072) es | [3072,3712) dec | [3712,3776) ms | [3776,4288) wr | [4288,4800) init
__global__ __launch_bounds__(256) void prolog_k(
    const float* __restrict__ x, const float* __restrict__ c0,
    const float* __restrict__ h0e, const float* __restrict__ h0d,
    const float* __restrict__ Wih_e, const float* __restrict__ Whh_e,
    const float* __restrict__ Wih_d, const float* __restrict__ Whh_d,
    const float* __restrict__ Wmu, const float* __restrict__ Wsig,
    const float* __restrict__ Wwr_f,
    float* __restrict__ c_t, float* __restrict__ c_enc, float* __restrict__ c_dec,
    bf16* __restrict__ negs, bf16* __restrict__ hh, bf16* __restrict__ x_bf,
    bf16* __restrict__ wxh, bf16* __restrict__ wsum, bf16* __restrict__ wcat,
    bf16* __restrict__ wdz, bf16* __restrict__ wdh, bf16* __restrict__ wms,
    bf16* __restrict__ wwr)
{
    const int bid = blockIdx.x;
    if (bid < 3072) {
        const int base_id = bid * 256 + threadIdx.x;
#pragma unroll
        for (int u = 0; u < 4; ++u) {
            int id = base_id + u * 786432;
            int np = id / 768, c = (id - np * 768) * 8;
            int n = ((np & 3) << 10) + (np >> 2);
            if (c < 4096) {
                const float* sx = Wih_e + (size_t)n * 9216 + c;
                const float* sh = sx + 4096;
                float4 a = *(const float4*)sh, b = *(const float4*)(sh + 4);
                float4 e = *(const float4*)sx, f = *(const float4*)(sx + 4);
                bf16x8 vh = { (bf16)a.x, (bf16)a.y, (bf16)a.z, (bf16)a.w,
                              (bf16)b.x, (bf16)b.y, (bf16)b.z, (bf16)b.w };
                bf16x8 vs = { (bf16)(a.x + e.x), (bf16)(a.y + e.y), (bf16)(a.z + e.z), (bf16)(a.w + e.w),
                              (bf16)(b.x + f.x), (bf16)(b.y + f.y), (bf16)(b.z + f.z), (bf16)(b.w + f.w) };
                *(bf16x8*)(wxh  + (size_t)np * 4096 + c) = vh;
                *(bf16x8*)(wsum + (size_t)np * 4096 + c) = vs;
            } else if (c < 5120) {
                *(bf16x8*)(wcat + (size_t)np * 2048 + (c - 4096)) =
                    cvt8(Wih_e + (size_t)n * 9216 + 8192 + (c - 4096));
            } else {
                *(bf16x8*)(wcat + (size_t)np * 2048 + 1024 + (c - 5120)) =
                    cvt8(Whh_e + (size_t)n * 1024 + (c - 5120));
            }
        }
        return;
    }
    if (bid < 3712) {
        const int base_id = (bid - 3072) * 256 + threadIdx.x;
#pragma unroll
        for (int u = 0; u < 4; ++u) {
            int id = base_id + u * 163840;
            int np = id / 160, c = (id - np * 160) * 8;
            int n = ((np & 3) << 10) + (np >> 2);
            if (c < 256)
                *(bf16x8*)(wdz + (size_t)np * 256 + c) = cvt8(Wih_d + (size_t)n * 256 + c);
            else
                *(bf16x8*)(wdh + (size_t)np * 1024 + (c - 256)) =
                    cvt8(Whh_d + (size_t)n * 1024 + (c - 256));
        }
        return;
    }
    if (bid < 3776) {
        const int base_id = (bid - 3712) * 256 + threadIdx.x;
#pragma unroll
        for (int u = 0; u < 4; ++u) {
            int id = base_id + u * 16384;
            int np = id >> 7, c = (id & 127) * 8;
            int zi = np >> 1;
            const float* src = ((np & 1) ? Wsig : Wmu) + (size_t)zi * 1024 + c;
            *(bf16x8*)(wms + (size_t)np * 1024 + c) = cvt8(src);
        }
        return;
    }
    if (bid < 4288) {
        const int base_id = (bid - 3776) * 256 + threadIdx.x;
#pragma unroll
        for (int u = 0; u < 4; ++u) {
            int id = base_id + u * 131072;
            *(bf16x8*)(wwr + (size_t)id * 8) = cvt8(Wwr_f + (size_t)id * 8);
        }
        return;
    }
    // init role
    const int base_id = (bid - 4288) * 256 + threadIdx.x;
#pragma unroll
    for (int u = 0; u < 4; ++u) {
        int i = base_id + u * 131072;
        int n = i & 4095;
        float c = c0[n];
        c_t[i] = c;
        negs[i] = (bf16)(-sigf(c));
        x_bf[i] = (bf16)x[i];
        if (i < PBH) {
            int row = i >> 10, j = i & 1023;
            c_enc[i] = 0.f;
            c_dec[i] = 0.f;
            hh[(size_t)row * 2048 + j]        = (bf16)h0d[j];
            hh[(size_t)row * 2048 + 1024 + j] = (bf16)h0e[j];
        }
    }
}

// ---------------- launch ----------------
extern "C" void kernel_launch(void* const* d_in, const int* in_sizes, int n_in,
                              void* d_out, int out_size, void* d_ws, size_t ws_size,
                              hipStream_t stream) {
    const float* x      = (const float*)d_in[0];
    const float* eps    = (const float*)d_in[1];
    const float* c0     = (const float*)d_in[2];
    const float* h0e    = (const float*)d_in[3];
    const float* h0d    = (const float*)d_in[4];
    const float* W_ih_e = (const float*)d_in[5];
    const float* b_ih_e = (const float*)d_in[6];
    const float* W_hh_e = (const float*)d_in[7];
    const float* b_hh_e = (const float*)d_in[8];
    const float* W_mu   = (const float*)d_in[9];
    const float* b_mu   = (const float*)d_in[10];
    const float* W_sig  = (const float*)d_in[11];
    const float* b_sig  = (const float*)d_in[12];
    const float* W_ih_d = (const float*)d_in[13];
    const float* b_ih_d = (const float*)d_in[14];
    const float* W_hh_d = (const float*)d_in[15];
    const float* b_hh_d = (const float*)d_in[16];
    const float* W_wr   = (const float*)d_in[17];
    const float* b_wr   = (const float*)d_in[18];
    float* out = (float*)d_out;

    float* f = (float*)d_ws;
    float* c_t   = f; f += SLICE;
    float* base  = f; f += SLICE;
    float* pP    = f; f += (size_t)8 * SLICE;    // fp32 prologue partials (z=8)
    float* c_enc = f; f += 131072;
    float* c_dec = f; f += 131072;
    bf16* bp    = (bf16*)f;
    bf16* encP  = bp; bp += (size_t)12 * SLICE;  // 0-7: kA; 8-11: hdhe
    bf16* decP  = bp; bp += (size_t)2 * SLICE;   // gdhh slices
    bf16* wrP   = bp; bp += (size_t)2 * SLICE;
    bf16* negs  = bp; bp += (size_t)B_ * 4096;
    bf16* hh    = bp; bp += (size_t)B_ * 2048;   // [hdec | henc] per row
    bf16* zbf   = bp; bp += (size_t)B_ * 256;
    bf16* x_bf  = bp; bp += (size_t)B_ * 4096;
    bf16* Wxh   = bp; bp += (size_t)4096 * 4096;
    bf16* Wsum  = bp; bp += (size_t)4096 * 4096;
    bf16* Wcat  = bp; bp += (size_t)4096 * 2048;
    bf16* Wdz   = bp; bp += (size_t)4096 * 256;
    bf16* Wdh   = bp; bp += (size_t)4096 * 1024;
    bf16* Wms   = bp; bp += (size_t)512 * 1024;
    bf16* Wwr   = bp; bp += (size_t)4096 * 1024;

    dim3 blk(256);

    // merged prologue: init + all weight packing (grid-stride 4 units/thread)
    prolog_k<<<dim3(4800), blk, 0, stream>>>(
        x, c0, h0e, h0d, W_ih_e, W_hh_e, W_ih_d, W_hh_d, W_mu, W_sig, W_wr,
        c_t, c_enc, c_dec, negs, hh, x_bf,
        Wxh, Wsum, Wcat, Wdz, Wdh, Wms, Wwr);

    // base = b_ih_e + b_hh_e + x @ Wsum^T  (gate-interleaved cols), fp32 z=8
    gemm64_k<<<dim3(64, 2, 8), blk, 0, stream>>>(x_bf, 4096, Wsum, 4096, 512, pP);
    fin0_k<<<dim3(512), blk, 0, stream>>>(pP, base, b_ih_e, b_hh_e);

    // preloop: hdhe (encP 8-11) + gdhh (decP 0-1) from initial hh
    kE_k<<<dim3(64, 2, 6), blk, 0, stream>>>(hh, Wwr, Wcat, Wdh, wrP, encP, decP, 2);

    for (int t = 0; t < T_; ++t) {
        // kA: negs @ Wxh^T (K=4096), z=8, Kc=512 -> encP slices 0-7
        gemm64b_k<<<dim3(64, 2, 8), blk, 0, stream>>>(negs, 4096, Wxh, 4096, 512, encP);
        // kB: sum 12 slices + base -> enc LSTM -> henc
        kB_k<<<dim3(256), blk, 0, stream>>>(encP, base, c_enc, hh);
        // kC: mu/sigma + reparam -> zbf
        kC_k<<<dim3(16), blk, 0, stream>>>(hh, Wms, b_mu, b_sig,
                                           eps + (size_t)t * (B_ * 256), zbf);
        // kD: dec z-GEMM + gdhh slices + LSTM -> hdec
        kD_k<<<dim3(128), blk, 0, stream>>>(zbf, Wdz, decP, b_ih_d, b_hh_d, c_dec, hh);
        // kE: wr (z=2) + hdhe (z=4) + gdhh (z=2), all nk=8
        kE_k<<<dim3(64, 2, 8), blk, 0, stream>>>(hh, Wwr, Wcat, Wdh, wrP, encP, decP, 0);
        // kF: c_t += wr + b_wr -> negs (+ out at last step)
        kF_k<<<dim3(512), blk, 0, stream>>>(wrP, b_wr, c_t, negs,
                                            (t == T_ - 1) ? out : nullptr);
    }
}

// Round 19
// 770.241 us; speedup vs baseline: 1.0810x; 1.0539x over previous
//
#include <hip/hip_runtime.h>

#define B_   128
#define T_   16

typedef __bf16 bf16;
typedef __bf16 bf16x4 __attribute__((ext_vector_type(4)));
typedef __bf16 bf16x8 __attribute__((ext_vector_type(8)));
typedef float f32x4 __attribute__((ext_vector_type(4)));

#define GLL(SRC, DST) __builtin_amdgcn_global_load_lds( \
    (const __attribute__((address_space(1))) void*)(SRC), \
    (__attribute__((address_space(3))) void*)(DST), 16, 0, 0)

#define MFMA __builtin_amdgcn_mfma_f32_16x16x32_bf16
#define SLICE 524288   // 128*4096 elements per partial slice

__device__ __forceinline__ float sigf(float x) { return 1.f / (1.f + expf(-x)); }

// ---------------------------------------------------------------------------
// 64x64-tile GEMM core: BK=64, dbuf 32KB LDS, 4 waves x 32x32.
// T4 counted-vmcnt: next-stage loads stay in flight across the barrier.
// Per iter: stage(next) -> vmcnt(4) (cur landed) -> s_barrier -> MFMA -> s_barrier.
// ---------------------------------------------------------------------------
__device__ __forceinline__ void core64(
    bf16 (&As)[2][4096], bf16 (&Bs)[2][4096],
    const bf16* __restrict__ Ab, int lda,
    const bf16* __restrict__ Wb, int ldw,
    int nk, f32x4 (&acc)[4])
{
    const int tid = threadIdx.x, lane = tid & 63, wave = tid >> 6;
    const int srow = lane >> 3;
    const int scol = ((lane & 7) ^ srow) << 3;     // pre-swizzled source col
    const int wr = wave & 1, wc = wave >> 1;
    const int ln = lane & 15;
    const int rA0 = wr * 32 + ln;
    const int rB0 = wc * 32 + ln;
    const int swz = (lane & 7) << 4;
    const int kq  = (lane >> 4) << 4;

    auto stage = [&](int b, int koff) {
        int c0 = wave, c1 = wave + 4;
        int ra0 = c0 * 8 + srow, ra1 = c1 * 8 + srow;
        GLL(Ab + (size_t)ra0 * lda + koff + scol, &As[b][c0 * 512]);
        GLL(Ab + (size_t)ra1 * lda + koff + scol, &As[b][c1 * 512]);
        GLL(Wb + (size_t)ra0 * ldw + koff + scol, &Bs[b][c0 * 512]);
        GLL(Wb + (size_t)ra1 * ldw + koff + scol, &Bs[b][c1 * 512]);
    };

    stage(0, 0);
    int bq = 0;
    for (int it = 0; it < nk; ++it) {
        if (it + 1 < nk) {
            stage(bq ^ 1, (it + 1) << 6);          // 4 more loads in flight
            asm volatile("s_waitcnt vmcnt(4)" ::: "memory");   // cur landed
        } else {
            asm volatile("s_waitcnt vmcnt(0)" ::: "memory");
        }
        __builtin_amdgcn_s_barrier();              // all waves' cur rows valid
        const bf16* as = As[bq];
        const bf16* bs = Bs[bq];
#pragma unroll
        for (int k2 = 0; k2 < 2; ++k2) {
            const int co = (((k2 << 6) | kq) ^ swz) >> 1;
            bf16x8 a0 = *(const bf16x8*)&as[rA0 * 64 + co];
            bf16x8 a1 = *(const bf16x8*)&as[(rA0 + 16) * 64 + co];
            bf16x8 b0 = *(const bf16x8*)&bs[rB0 * 64 + co];
            bf16x8 b1 = *(const bf16x8*)&bs[(rB0 + 16) * 64 + co];
            acc[0] = MFMA(a0, b0, acc[0], 0, 0, 0);
            acc[1] = MFMA(a0, b1, acc[1], 0, 0, 0);
            acc[2] = MFMA(a1, b0, acc[2], 0, 0, 0);
            acc[3] = MFMA(a1, b1, acc[3], 0, 0, 0);
        }
        __builtin_amdgcn_s_barrier();              // compute done before re-stage
        bq ^= 1;
    }
}

__device__ __forceinline__ void store64f(float* __restrict__ P, int bm, int bn,
                                         f32x4 (&acc)[4])
{
    const int lane = threadIdx.x & 63, wave = threadIdx.x >> 6;
    const int wr = wave & 1, wc = wave >> 1;
    const int ln = lane & 15, q = lane >> 4;
    const int row0 = bm + wr * 32 + q * 4;
    const int col0 = bn + wc * 32 + ln;
#pragma unroll
    for (int r = 0; r < 4; ++r) {
        P[(size_t)(row0 + r) * 4096 + col0]           = acc[0][r];
        P[(size_t)(row0 + r) * 4096 + col0 + 16]      = acc[1][r];
        P[(size_t)(row0 + 16 + r) * 4096 + col0]      = acc[2][r];
        P[(size_t)(row0 + 16 + r) * 4096 + col0 + 16] = acc[3][r];
    }
}

__device__ __forceinline__ void store64b(bf16* __restrict__ P, int bm, int bn,
                                         f32x4 (&acc)[4])
{
    const int lane = threadIdx.x & 63, wave = threadIdx.x >> 6;
    const int wr = wave & 1, wc = wave >> 1;
    const int ln = lane & 15, q = lane >> 4;
    const int row0 = bm + wr * 32 + q * 4;
    const int col0 = bn + wc * 32 + ln;
#pragma unroll
    for (int r = 0; r < 4; ++r) {
        P[(size_t)(row0 + r) * 4096 + col0]           = (bf16)acc[0][r];
        P[(size_t)(row0 + r) * 4096 + col0 + 16]      = (bf16)acc[1][r];
        P[(size_t)(row0 + 16 + r) * 4096 + col0]      = (bf16)acc[2][r];
        P[(size_t)(row0 + 16 + r) * 4096 + col0 + 16] = (bf16)acc[3][r];
    }
}

// split-K GEMM -> fp32 slices (prologue base). grid (64 nt, 2 mt, z)
__global__ __launch_bounds__(256) void gemm64_k(
    const bf16* __restrict__ A, int lda,
    const bf16* __restrict__ W, int ldw, int Kc,
    float* __restrict__ P)
{
    __shared__ bf16 As[2][4096], Bs[2][4096];
    const int nt = blockIdx.x, mt = blockIdx.y, zz = blockIdx.z;
    f32x4 acc[4];
#pragma unroll
    for (int i = 0; i < 4; ++i) acc[i] = (f32x4){0.f, 0.f, 0.f, 0.f};
    const bf16* Ab = A + (size_t)mt * 64 * lda + (size_t)zz * Kc;
    const bf16* Wb = W + (size_t)nt * 64 * ldw + (size_t)zz * Kc;
    core64(As, Bs, Ab, lda, Wb, ldw, Kc >> 6, acc);
    store64f(P + (size_t)zz * SLICE, mt * 64, nt * 64, acc);
}

// split-K GEMM -> bf16 slices (kA). grid (64 nt, 2 mt, z)
__global__ __launch_bounds__(256) void gemm64b_k(
    const bf16* __restrict__ A, int lda,
    const bf16* __restrict__ W, int ldw, int Kc,
    bf16* __restrict__ P)
{
    __shared__ bf16 As[2][4096], Bs[2][4096];
    const int nt = blockIdx.x, mt = blockIdx.y, zz = blockIdx.z;
    f32x4 acc[4];
#pragma unroll
    for (int i = 0; i < 4; ++i) acc[i] = (f32x4){0.f, 0.f, 0.f, 0.f};
    const bf16* Ab = A + (size_t)mt * 64 * lda + (size_t)zz * Kc;
    const bf16* Wb = W + (size_t)nt * 64 * ldw + (size_t)zz * Kc;
    core64(As, Bs, Ab, lda, Wb, ldw, Kc >> 6, acc);
    store64b(P + (size_t)zz * SLICE, mt * 64, nt * 64, acc);
}

// ---------------------------------------------------------------------------
// kE: end-of-step combined GEMMs, all nk=8, bf16 slices (R12-proven).
// ---------------------------------------------------------------------------
__global__ __launch_bounds__(256) void kE_k(
    const bf16* __restrict__ hh,   const bf16* __restrict__ Wwr,
    const bf16* __restrict__ Wcat, const bf16* __restrict__ Wdh,
    bf16* __restrict__ wrP, bf16* __restrict__ encP, bf16* __restrict__ decP,
    int zoff)
{
    __shared__ bf16 As[2][4096], Bs[2][4096];
    const int nt = blockIdx.x, mt = blockIdx.y, zz = blockIdx.z + zoff;
    f32x4 acc[4];
#pragma unroll
    for (int i = 0; i < 4; ++i) acc[i] = (f32x4){0.f, 0.f, 0.f, 0.f};

    const bf16* Ab;
    const bf16* Wb;
    int ldw;
    bf16* P;
    if (zz < 2) {
        Ab = hh + (size_t)mt * 64 * 2048 + zz * 512;
        Wb = Wwr + (size_t)nt * 64 * 1024 + zz * 512;
        ldw = 1024; P = wrP + (size_t)zz * SLICE;
    } else if (zz < 6) {
        int s = zz - 2;
        Ab = hh + (size_t)mt * 64 * 2048 + s * 512;
        Wb = Wcat + (size_t)nt * 64 * 2048 + s * 512;
        ldw = 2048; P = encP + (size_t)(8 + s) * SLICE;
    } else {
        int g = zz - 6;
        Ab = hh + (size_t)mt * 64 * 2048 + g * 512;
        Wb = Wdh + (size_t)nt * 64 * 1024 + g * 512;
        ldw = 1024; P = decP + (size_t)g * SLICE;
    }
    core64(As, Bs, Ab, 2048, Wb, ldw, 8, acc);
    store64b(P, mt * 64, nt * 64, acc);
}

// ---------------------------------------------------------------------------
// consumers
// ---------------------------------------------------------------------------
// fin0: sum 8 fp32 slices + both enc biases -> base fp32. grid 512.
__global__ __launch_bounds__(256) void fin0_k(
    const float* __restrict__ P, float* __restrict__ base,
    const float* __restrict__ b1, const float* __restrict__ b2)
{
    const int i = blockIdx.x * 256 + threadIdx.x;
    const int row = i >> 10, j = i & 1023;
    const size_t off = (size_t)row * 4096 + (j << 2);
    float s0 = 0.f, s1 = 0.f, s2 = 0.f, s3 = 0.f;
#pragma unroll
    for (int z = 0; z < 8; ++z) {
        float4 p = *(const float4*)(P + (size_t)z * SLICE + off);
        s0 += p.x; s1 += p.y; s2 += p.z; s3 += p.w;
    }
    base[off + 0] = s0 + b1[j]        + b2[j];
    base[off + 1] = s1 + b1[1024 + j] + b2[1024 + j];
    base[off + 2] = s2 + b1[2048 + j] + b2[2048 + j];
    base[off + 3] = s3 + b1[3072 + j] + b2[3072 + j];
}

// kB: sum encP bf16 slices 0-11 (x8 vectorized) + base -> enc LSTM -> henc.
__global__ __launch_bounds__(256) void kB_k(
    const bf16* __restrict__ encP, const float* __restrict__ base,
    float* __restrict__ c_enc, bf16* __restrict__ hh)
{
    const int i = blockIdx.x * 256 + threadIdx.x;   // 0..65535
    const int row = i >> 9, li = i & 511;
    const size_t off = (size_t)row * 4096 + (li << 3);
    float s[8] = {0.f, 0.f, 0.f, 0.f, 0.f, 0.f, 0.f, 0.f};
#pragma unroll
    for (int z = 0; z < 12; ++z) {
        bf16x8 p = *(const bf16x8*)(encP + (size_t)z * SLICE + off);
#pragma unroll
        for (int k = 0; k < 8; ++k) s[k] += (float)p[k];
    }
    float4 bb0 = *(const float4*)(base + off);
    float4 bb1 = *(const float4*)(base + off + 4);
    const int j0 = li << 1;                          // gate-quad index
    {
        float gi = s[0] + bb0.x, gf = s[1] + bb0.y, gg = s[2] + bb0.z, go = s[3] + bb0.w;
        int ci = row * 1024 + j0;
        float cn = sigf(gf) * c_enc[ci] + sigf(gi) * tanhf(gg);
        c_enc[ci] = cn;
        hh[(size_t)row * 2048 + 1024 + j0] = (bf16)(sigf(go) * tanhf(cn));
    }
    {
        float gi = s[4] + bb1.x, gf = s[5] + bb1.y, gg = s[6] + bb1.z, go = s[7] + bb1.w;
        int ci = row * 1024 + j0 + 1;
        float cn = sigf(gf) * c_enc[ci] + sigf(gi) * tanhf(gg);
        c_enc[ci] = cn;
        hh[(size_t)row * 2048 + 1024 + j0 + 1] = (bf16)(sigf(go) * tanhf(cn));
    }
}

// kF: c_t += wrP0+wrP1 (bf16) + b_wr -> negs; optional out
__global__ __launch_bounds__(256) void kF_k(
    const bf16* __restrict__ wrP, const float* __restrict__ b_wr,
    float* __restrict__ c_t, bf16* __restrict__ negs, float* __restrict__ outp)
{
    const int qi = blockIdx.x * 256 + threadIdx.x;
    const int row = qi >> 10, cq = qi & 1023;
    const size_t off = (size_t)row * 4096 + (cq << 2);
    bf16x4 p0 = *(const bf16x4*)(wrP + off);
    bf16x4 p1 = *(const bf16x4*)(wrP + SLICE + off);
    float4 cv = *(const float4*)(c_t + off);
    float4 bw = *(const float4*)(b_wr + (cq << 2));
    float v0 = cv.x + (float)p0[0] + (float)p1[0] + bw.x;
    float v1 = cv.y + (float)p0[1] + (float)p1[1] + bw.y;
    float v2 = cv.z + (float)p0[2] + (float)p1[2] + bw.z;
    float v3 = cv.w + (float)p0[3] + (float)p1[3] + bw.w;
    *(float4*)(c_t + off) = make_float4(v0, v1, v2, v3);
    negs[off + 0] = (bf16)(-sigf(v0));
    negs[off + 1] = (bf16)(-sigf(v1));
    negs[off + 2] = (bf16)(-sigf(v2));
    negs[off + 3] = (bf16)(-sigf(v3));
    if (outp)
        *(float4*)(outp + off) = make_float4(sigf(v0), sigf(v1), sigf(v2), sigf(v3));
}

// ---------------------------------------------------------------------------
// kC: mu/sigma GEMM (128x32 tile, K=1024 as 4x256) + reparam -> zbf. grid 16.
// ---------------------------------------------------------------------------
struct SmemG32 {
    bf16 As[4][128][64];   // 64 KB
    bf16 Ws[4][32][64];    // 16 KB
};

__global__ __launch_bounds__(256) void kC_k(
    const bf16* __restrict__ hh, const bf16* __restrict__ Wms,
    const float* __restrict__ b_mu, const float* __restrict__ b_sig,
    const float* __restrict__ eps_t, bf16* __restrict__ zbf)
{
    __shared__ SmemG32 sm;
    const int nt = blockIdx.x;
    const int tid = threadIdx.x, lane = tid & 63, wave = tid >> 6;
    const int srow = lane >> 3, scol = ((lane & 7) ^ srow) << 3;
    const int ln = lane & 15, kq = (lane >> 4) << 4;
    const int swz = (lane & 7) << 4;
    const int rA = wave * 32 + ln;
    const bf16* Wb = Wms + (size_t)nt * 32 * 1024;
    const bf16* Ab = hh + 1024;

    f32x4 acc[2][2];
#pragma unroll
    for (int m = 0; m < 2; ++m)
#pragma unroll
        for (int n = 0; n < 2; ++n) acc[m][n] = (f32x4){0.f, 0.f, 0.f, 0.f};

    for (int it = 0; it < 4; ++it) {
        if (it) __syncthreads();
        const int koff = it * 256;
#pragma unroll
        for (int kc = 0; kc < 4; ++kc) {
            const int kg = koff + kc * 64 + scol;
#pragma unroll
            for (int i = 0; i < 4; ++i) {
                int rb = i * 32 + wave * 8;
                GLL(Ab + (size_t)(rb + srow) * 2048 + kg, &sm.As[kc][rb][0]);
            }
            GLL(Wb + (size_t)(wave * 8 + srow) * 1024 + kg, &sm.Ws[kc][wave * 8][0]);
        }
        __syncthreads();
#pragma unroll
        for (int kc = 0; kc < 4; ++kc)
#pragma unroll
            for (int k2 = 0; k2 < 2; ++k2) {
                const int co = (((k2 << 6) | kq) ^ swz) >> 1;
                bf16x8 a0 = *(const bf16x8*)&sm.As[kc][rA][co];
                bf16x8 a1 = *(const bf16x8*)&sm.As[kc][rA + 16][co];
                bf16x8 b0 = *(const bf16x8*)&sm.Ws[kc][ln][co];
                bf16x8 b1 = *(const bf16x8*)&sm.Ws[kc][ln + 16][co];
                acc[0][0] = MFMA(a0, b0, acc[0][0], 0, 0, 0);
                acc[0][1] = MFMA(a0, b1, acc[0][1], 0, 0, 0);
                acc[1][0] = MFMA(a1, b0, acc[1][0], 0, 0, 0);
                acc[1][1] = MFMA(a1, b1, acc[1][1], 0, 0, 0);
            }
    }
    __syncthreads();

    float* Cl = (float*)&sm;
    const int q = lane >> 4;
#pragma unroll
    for (int f = 0; f < 2; ++f)
#pragma unroll
        for (int n = 0; n < 2; ++n)
#pragma unroll
            for (int r = 0; r < 4; ++r)
                Cl[(wave * 32 + f * 16 + q * 4 + r) * 33 + n * 16 + ln] = acc[f][n][r];
    __syncthreads();

#pragma unroll
    for (int it = 0; it < 8; ++it) {
        int li = it * 256 + tid;
        int row = li >> 4, zl = li & 15;
        int zi = nt * 16 + zl;
        float mu = Cl[row * 33 + zl * 2]     + b_mu[zi];
        float ls = Cl[row * 33 + zl * 2 + 1] + b_sig[zi];
        float z = eps_t[row * 256 + zi] * expf(ls) + mu;
        zbf[(size_t)row * 256 + zi] = (bf16)z;
    }
}

// ---------------------------------------------------------------------------
// kD: dec z-GEMM (64x64 tile, K=256 one-shot via core64) + gdhh slices +
// biases + LSTM -> hdec (hh[j]). grid 128, 32 KB LDS.
// ---------------------------------------------------------------------------
struct SmemK { bf16 A[2][4096]; bf16 B[2][4096]; };   // 32 KB

__global__ __launch_bounds__(256) void kD_k(
    const bf16* __restrict__ zbf, const bf16* __restrict__ Wdz,
    const bf16* __restrict__ decP,
    const float* __restrict__ b_ihd, const float* __restrict__ b_hhd,
    float* __restrict__ c_dec, bf16* __restrict__ hh)
{
    __shared__ SmemK sm;
    const int bid = blockIdx.x;
    const int mt = bid & 1, nt = bid >> 1;      // rows mt*64, cols(n') nt*64
    const int tid = threadIdx.x, lane = tid & 63, wave = tid >> 6;
    const int wr = wave & 1, wc = wave >> 1;
    const int ln = lane & 15, q = lane >> 4;

    const bf16* Ab = zbf + (size_t)mt * 64 * 256;
    const bf16* Wb = Wdz + (size_t)nt * 64 * 256;
    f32x4 acc[4];
#pragma unroll
    for (int i = 0; i < 4; ++i) acc[i] = (f32x4){0.f, 0.f, 0.f, 0.f};
    core64(sm.A, sm.B, Ab, 256, Wb, 256, 4, acc);

    __syncthreads();
    float* Cl = (float*)&sm;                     // 64 x 66 fp32 (16.9 KB)
    const int r0 = wr * 32 + q * 4;
    const int c0 = wc * 32 + ln;
#pragma unroll
    for (int r = 0; r < 4; ++r) {
        Cl[(r0 + r) * 66 + c0]           = acc[0][r];
        Cl[(r0 + r) * 66 + c0 + 16]      = acc[1][r];
        Cl[(r0 + 16 + r) * 66 + c0]      = acc[2][r];
        Cl[(r0 + 16 + r) * 66 + c0 + 16] = acc[3][r];
    }
    __syncthreads();

#pragma unroll
    for (int it = 0; it < 4; ++it) {
        int li = it * 256 + tid;                 // 0..1023
        int lrow = li >> 4, jl = li & 15;
        int row = mt * 64 + lrow;
        int np0 = nt * 64 + jl * 4;
        int J = np0 >> 2;
        const float* cr = &Cl[lrow * 66 + jl * 4];
        const bf16* gp = decP + (size_t)row * 4096 + np0;
        bf16x4 g0v = *(const bf16x4*)gp;
        bf16x4 g1v = *(const bf16x4*)(gp + SLICE);
        float gi = cr[0] + (float)g0v[0] + (float)g1v[0] + b_ihd[J]        + b_hhd[J];
        float gf = cr[1] + (float)g0v[1] + (float)g1v[1] + b_ihd[1024 + J] + b_hhd[1024 + J];
        float gg = cr[2] + (float)g0v[2] + (float)g1v[2] + b_ihd[2048 + J] + b_hhd[2048 + J];
        float go = cr[3] + (float)g0v[3] + (float)g1v[3] + b_ihd[3072 + J] + b_hhd[3072 + J];
        int ci = row * 1024 + J;
        float cn = sigf(gf) * c_dec[ci] + sigf(gi) * tanhf(gg);
        c_dec[ci] = cn;
        hh[(size_t)row * 2048 + J] = (bf16)(sigf(go) * tanhf(cn));
    }
}

// ---------------- merged prologue: init + all weight packing (R16 exact) ----
#define PBL (B_ * 4096)
#define PBH (B_ * 1024)

__device__ __forceinline__ bf16x8 cvt8(const float* s) {
    float4 a = *(const float4*)s, b = *(const float4*)(s + 4);
    bf16x8 v = { (bf16)a.x, (bf16)a.y, (bf16)a.z, (bf16)a.w,
                 (bf16)b.x, (bf16)b.y, (bf16)b.z, (bf16)b.w };
    return v;
}

// roles by bid: [0,12288) conv_es | +2560 conv_dec | +256 conv_ms |
//               +2048 conv_wr | +2048 init      (total 19200)
__global__ __launch_bounds__(256) void prolog_k(
    const float* __restrict__ x, const float* __restrict__ c0,
    const float* __restrict__ h0e, const float* __restrict__ h0d,
    const float* __restrict__ Wih_e, const float* __restrict__ Whh_e,
    const float* __restrict__ Wih_d, const float* __restrict__ Whh_d,
    const float* __restrict__ Wmu, const float* __restrict__ Wsig,
    const float* __restrict__ Wwr_f,
    float* __restrict__ c_t, float* __restrict__ c_enc, float* __restrict__ c_dec,
    bf16* __restrict__ negs, bf16* __restrict__ hh, bf16* __restrict__ x_bf,
    bf16* __restrict__ wxh, bf16* __restrict__ wsum, bf16* __restrict__ wcat,
    bf16* __restrict__ wdz, bf16* __restrict__ wdh, bf16* __restrict__ wms,
    bf16* __restrict__ wwr)
{
    const int bid = blockIdx.x;
    if (bid < 12288) {
        int id = bid * 256 + threadIdx.x;
        int np = id / 768, c = (id - np * 768) * 8;
        int n = ((np & 3) << 10) + (np >> 2);
        if (c < 4096) {
            const float* sx = Wih_e + (size_t)n * 9216 + c;
            const float* sh = sx + 4096;
            float4 a = *(const float4*)sh, b = *(const float4*)(sh + 4);
            float4 e = *(const float4*)sx, f = *(const float4*)(sx + 4);
            bf16x8 vh = { (bf16)a.x, (bf16)a.y, (bf16)a.z, (bf16)a.w,
                          (bf16)b.x, (bf16)b.y, (bf16)b.z, (bf16)b.w };
            bf16x8 vs = { (bf16)(a.x + e.x), (bf16)(a.y + e.y), (bf16)(a.z + e.z), (bf16)(a.w + e.w),
                          (bf16)(b.x + f.x), (bf16)(b.y + f.y), (bf16)(b.z + f.z), (bf16)(b.w + f.w) };
            *(bf16x8*)(wxh  + (size_t)np * 4096 + c) = vh;
            *(bf16x8*)(wsum + (size_t)np * 4096 + c) = vs;
        } else if (c < 5120) {
            *(bf16x8*)(wcat + (size_t)np * 2048 + (c - 4096)) =
                cvt8(Wih_e + (size_t)n * 9216 + 8192 + (c - 4096));
        } else {
            *(bf16x8*)(wcat + (size_t)np * 2048 + 1024 + (c - 5120)) =
                cvt8(Whh_e + (size_t)n * 1024 + (c - 5120));
        }
        return;
    }
    if (bid < 12288 + 2560) {
        int id = (bid - 12288) * 256 + threadIdx.x;
        int np = id / 160, c = (id - np * 160) * 8;
        int n = ((np & 3) << 10) + (np >> 2);
        if (c < 256)
            *(bf16x8*)(wdz + (size_t)np * 256 + c) = cvt8(Wih_d + (size_t)n * 256 + c);
        else
            *(bf16x8*)(wdh + (size_t)np * 1024 + (c - 256)) =
                cvt8(Whh_d + (size_t)n * 1024 + (c - 256));
        return;
    }
    if (bid < 12288 + 2560 + 256) {
        int id = (bid - 12288 - 2560) * 256 + threadIdx.x;
        int np = id >> 7, c = (id & 127) * 8;
        int zi = np >> 1;
        const float* src = ((np & 1) ? Wsig : Wmu) + (size_t)zi * 1024 + c;
        *(bf16x8*)(wms + (size_t)np * 1024 + c) = cvt8(src);
        return;
    }
    if (bid < 12288 + 2560 + 256 + 2048) {
        int id = (bid - 12288 - 2560 - 256) * 256 + threadIdx.x;
        *(bf16x8*)(wwr + (size_t)id * 8) = cvt8(Wwr_f + (size_t)id * 8);
        return;
    }
    // init role
    int i = (bid - 12288 - 2560 - 256 - 2048) * 256 + threadIdx.x;
    int n = i & 4095;
    float c = c0[n];
    c_t[i] = c;
    negs[i] = (bf16)(-sigf(c));
    x_bf[i] = (bf16)x[i];
    if (i < PBH) {
        int row = i >> 10, j = i & 1023;
        c_enc[i] = 0.f;
        c_dec[i] = 0.f;
        hh[(size_t)row * 2048 + j]        = (bf16)h0d[j];
        hh[(size_t)row * 2048 + 1024 + j] = (bf16)h0e[j];
    }
}

// ---------------- launch ----------------
extern "C" void kernel_launch(void* const* d_in, const int* in_sizes, int n_in,
                              void* d_out, int out_size, void* d_ws, size_t ws_size,
                              hipStream_t stream) {
    const float* x      = (const float*)d_in[0];
    const float* eps    = (const float*)d_in[1];
    const float* c0     = (const float*)d_in[2];
    const float* h0e    = (const float*)d_in[3];
    const float* h0d    = (const float*)d_in[4];
    const float* W_ih_e = (const float*)d_in[5];
    const float* b_ih_e = (const float*)d_in[6];
    const float* W_hh_e = (const float*)d_in[7];
    const float* b_hh_e = (const float*)d_in[8];
    const float* W_mu   = (const float*)d_in[9];
    const float* b_mu   = (const float*)d_in[10];
    const float* W_sig  = (const float*)d_in[11];
    const float* b_sig  = (const float*)d_in[12];
    const float* W_ih_d = (const float*)d_in[13];
    const float* b_ih_d = (const float*)d_in[14];
    const float* W_hh_d = (const float*)d_in[15];
    const float* b_hh_d = (const float*)d_in[16];
    const float* W_wr   = (const float*)d_in[17];
    const float* b_wr   = (const float*)d_in[18];
    float* out = (float*)d_out;

    float* f = (float*)d_ws;
    float* c_t   = f; f += SLICE;
    float* base  = f; f += SLICE;
    float* pP    = f; f += (size_t)8 * SLICE;    // fp32 prologue partials (z=8)
    float* c_enc = f; f += 131072;
    float* c_dec = f; f += 131072;
    bf16* bp    = (bf16*)f;
    bf16* encP  = bp; bp += (size_t)12 * SLICE;  // 0-7: kA; 8-11: hdhe
    bf16* decP  = bp; bp += (size_t)2 * SLICE;   // gdhh slices
    bf16* wrP   = bp; bp += (size_t)2 * SLICE;
    bf16* negs  = bp; bp += (size_t)B_ * 4096;
    bf16* hh    = bp; bp += (size_t)B_ * 2048;   // [hdec | henc] per row
    bf16* zbf   = bp; bp += (size_t)B_ * 256;
    bf16* x_bf  = bp; bp += (size_t)B_ * 4096;
    bf16* Wxh   = bp; bp += (size_t)4096 * 4096;
    bf16* Wsum  = bp; bp += (size_t)4096 * 4096;
    bf16* Wcat  = bp; bp += (size_t)4096 * 2048;
    bf16* Wdz   = bp; bp += (size_t)4096 * 256;
    bf16* Wdh   = bp; bp += (size_t)4096 * 1024;
    bf16* Wms   = bp; bp += (size_t)512 * 1024;
    bf16* Wwr   = bp; bp += (size_t)4096 * 1024;

    dim3 blk(256);

    // merged prologue: init + all weight packing (R16 exact)
    prolog_k<<<dim3(19200), blk, 0, stream>>>(
        x, c0, h0e, h0d, W_ih_e, W_hh_e, W_ih_d, W_hh_d, W_mu, W_sig, W_wr,
        c_t, c_enc, c_dec, negs, hh, x_bf,
        Wxh, Wsum, Wcat, Wdz, Wdh, Wms, Wwr);

    // base = b_ih_e + b_hh_e + x @ Wsum^T  (gate-interleaved cols), fp32 z=8
    gemm64_k<<<dim3(64, 2, 8), blk, 0, stream>>>(x_bf, 4096, Wsum, 4096, 512, pP);
    fin0_k<<<dim3(512), blk, 0, stream>>>(pP, base, b_ih_e, b_hh_e);

    // preloop: hdhe (encP 8-11) + gdhh (decP 0-1) from initial hh
    kE_k<<<dim3(64, 2, 6), blk, 0, stream>>>(hh, Wwr, Wcat, Wdh, wrP, encP, decP, 2);

    for (int t = 0; t < T_; ++t) {
        // kA: negs @ Wxh^T (K=4096), z=8, Kc=512 -> encP slices 0-7
        gemm64b_k<<<dim3(64, 2, 8), blk, 0, stream>>>(negs, 4096, Wxh, 4096, 512, encP);
        // kB: sum 12 slices + base -> enc LSTM -> henc
        kB_k<<<dim3(256), blk, 0, stream>>>(encP, base, c_enc, hh);
        // kC: mu/sigma + reparam -> zbf
        kC_k<<<dim3(16), blk, 0, stream>>>(hh, Wms, b_mu, b_sig,
                                           eps + (size_t)t * (B_ * 256), zbf);
        // kD: dec z-GEMM + gdhh slices + LSTM -> hdec
        kD_k<<<dim3(128), blk, 0, stream>>>(zbf, Wdz, decP, b_ih_d, b_hh_d, c_dec, hh);
        // kE: wr (z=2) + hdhe (z=4) + gdhh (z=2), all nk=8
        kE_k<<<dim3(64, 2, 8), blk, 0, stream>>>(hh, Wwr, Wcat, Wdh, wrP, encP, decP, 0);
        // kF: c_t += wr + b_wr -> negs (+ out at last step)
        kF_k<<<dim3(512), blk, 0, stream>>>(wrP, b_wr, c_t, negs,
                                            (t == T_ - 1) ? out : nullptr);
    }
}